// Round 1
// baseline (1714.063 us; speedup 1.0000x reference)
//
#include <hip/hip_runtime.h>

#define NN 50000
#define NE 800000
#define NG 128
#define IND 5
#define HID 64
#define EPSV 1e-5f

// ---------------- degree / norm ----------------
__global__ void k_deg_init(float* deg) {
    int i = blockIdx.x * blockDim.x + threadIdx.x;
    if (i < NN) deg[i] = 1.0f;   // self-loop weight 1
}

__global__ void k_deg_scatter(const int* __restrict__ dst, const float* __restrict__ w,
                              float* deg) {
    int e = blockIdx.x * blockDim.x + threadIdx.x;
    if (e < NE) atomicAdd(&deg[dst[e]], w[e]);
}

__global__ void k_dinv(float* deg) {
    int i = blockIdx.x * blockDim.x + threadIdx.x;
    if (i < NN) deg[i] = rsqrtf(deg[i]);   // deg >= 1 always
}

// ---------------- x @ W1  (N x 5 @ 5 x 64) ----------------
__global__ void k_gemm1(const float* __restrict__ x, const float* __restrict__ W1,
                        float* __restrict__ h) {
    __shared__ float Ws[IND * HID];
    for (int j = threadIdx.x; j < IND * HID; j += blockDim.x) Ws[j] = W1[j];
    __syncthreads();
    int gid = blockIdx.x * blockDim.x + threadIdx.x;
    if (gid >= NN * HID) return;
    int n = gid >> 6, hc = gid & 63;
    const float* xr = &x[n * IND];
    float acc = 0.f;
#pragma unroll
    for (int k = 0; k < IND; k++) acc += xr[k] * Ws[k * HID + hc];
    h[gid] = acc;
}

// ---------------- a @ W2  (N x 64 @ 64 x 64) ----------------
__global__ void k_gemm2(const float* __restrict__ a, const float* __restrict__ W,
                        float* __restrict__ out) {
    __shared__ float Ws[HID * HID];
    for (int j = threadIdx.x; j < HID * HID; j += blockDim.x) Ws[j] = W[j];
    __syncthreads();
    int gid = blockIdx.x * blockDim.x + threadIdx.x;
    if (gid >= NN * HID) return;
    int n = gid >> 6, hc = gid & 63;
    const float* ar = &a[n * HID];
    float acc = 0.f;
#pragma unroll 8
    for (int k = 0; k < HID; k++) acc += ar[k] * Ws[k * HID + hc];
    out[gid] = acc;
}

// ---------------- out = b + dinv^2 * h  (self loop + bias) ----------------
__global__ void k_init_out(const float* __restrict__ h, const float* __restrict__ dinv,
                           const float* __restrict__ b, float* __restrict__ out) {
    int gid = blockIdx.x * blockDim.x + threadIdx.x;   // over N*16 float4 units
    if (gid >= NN * 16) return;
    int n = gid >> 4, c4 = gid & 15;
    float di = dinv[n];
    float coef = di * di;
    float4 hv = ((const float4*)h)[gid];
    float4 bv = ((const float4*)b)[c4];
    float4 o;
    o.x = bv.x + coef * hv.x;
    o.y = bv.y + coef * hv.y;
    o.z = bv.z + coef * hv.z;
    o.w = bv.w + coef * hv.w;
    ((float4*)out)[gid] = o;
}

// ---------------- edge scatter: out[d] += dinv[s]*w*dinv[d] * h[s] ----------------
__global__ void k_scatter(const int* __restrict__ src, const int* __restrict__ dst,
                          const float* __restrict__ ew, const float* __restrict__ dinv,
                          const float* __restrict__ h, float* out) {
    int gid = blockIdx.x * blockDim.x + threadIdx.x;   // 16 lanes per edge
    int e = gid >> 4;
    if (e >= NE) return;
    int c4 = gid & 15;
    int s = src[e], d = dst[e];
    float norm = dinv[s] * ew[e] * dinv[d];
    float4 hv = ((const float4*)h)[s * 16 + c4];
    float* op = &out[d * 64 + c4 * 4];
    atomicAdd(op + 0, norm * hv.x);
    atomicAdd(op + 1, norm * hv.y);
    atomicAdd(op + 2, norm * hv.z);
    atomicAdd(op + 3, norm * hv.w);
}

// ---------------- BN(eval) + ReLU ----------------
__global__ void k_bnrelu(const float* __restrict__ in, float* __restrict__ outv,
                         const float* __restrict__ gamma, const float* __restrict__ beta,
                         const float* __restrict__ mean, const float* __restrict__ var) {
    int gid = blockIdx.x * blockDim.x + threadIdx.x;   // N*16 float4 units
    if (gid >= NN * 16) return;
    int c0 = (gid & 15) * 4;
    float4 v = ((const float4*)in)[gid];
    float4 o;
    {
        float sc = rsqrtf(var[c0 + 0] + EPSV) * gamma[c0 + 0];
        o.x = fmaxf((v.x - mean[c0 + 0]) * sc + beta[c0 + 0], 0.f);
    }
    {
        float sc = rsqrtf(var[c0 + 1] + EPSV) * gamma[c0 + 1];
        o.y = fmaxf((v.y - mean[c0 + 1]) * sc + beta[c0 + 1], 0.f);
    }
    {
        float sc = rsqrtf(var[c0 + 2] + EPSV) * gamma[c0 + 2];
        o.z = fmaxf((v.z - mean[c0 + 2]) * sc + beta[c0 + 2], 0.f);
    }
    {
        float sc = rsqrtf(var[c0 + 3] + EPSV) * gamma[c0 + 3];
        o.w = fmaxf((v.w - mean[c0 + 3]) * sc + beta[c0 + 3], 0.f);
    }
    ((float4*)outv)[gid] = o;
}

// ---------------- BN2 + ReLU + mean-pool accumulate ----------------
__global__ void k_pool(const float* __restrict__ in, const int* __restrict__ batch,
                       const float* __restrict__ gamma, const float* __restrict__ beta,
                       const float* __restrict__ mean, const float* __restrict__ var,
                       float* pool_sums, float* cnt) {
    int gid = blockIdx.x * blockDim.x + threadIdx.x;   // N*16 float4 units
    if (gid >= NN * 16) return;
    int n = gid >> 4, c4 = gid & 15;
    int c0 = c4 * 4;
    int g = batch[n];
    float4 v = ((const float4*)in)[gid];
    float r0, r1, r2, r3;
    {
        float sc = rsqrtf(var[c0 + 0] + EPSV) * gamma[c0 + 0];
        r0 = fmaxf((v.x - mean[c0 + 0]) * sc + beta[c0 + 0], 0.f);
    }
    {
        float sc = rsqrtf(var[c0 + 1] + EPSV) * gamma[c0 + 1];
        r1 = fmaxf((v.y - mean[c0 + 1]) * sc + beta[c0 + 1], 0.f);
    }
    {
        float sc = rsqrtf(var[c0 + 2] + EPSV) * gamma[c0 + 2];
        r2 = fmaxf((v.z - mean[c0 + 2]) * sc + beta[c0 + 2], 0.f);
    }
    {
        float sc = rsqrtf(var[c0 + 3] + EPSV) * gamma[c0 + 3];
        r3 = fmaxf((v.w - mean[c0 + 3]) * sc + beta[c0 + 3], 0.f);
    }
    float* pp = &pool_sums[g * HID + c0];
    atomicAdd(pp + 0, r0);
    atomicAdd(pp + 1, r1);
    atomicAdd(pp + 2, r2);
    atomicAdd(pp + 3, r3);
    if (c4 == 0) atomicAdd(&cnt[g], 1.0f);
}

// ---------------- final MLP: relu(pooled @ l1W + l1b) @ l2W + l2b ----------------
__global__ void k_mlp(const float* __restrict__ pool_sums, const float* __restrict__ cnt,
                      const float* __restrict__ l1W, const float* __restrict__ l1b,
                      const float* __restrict__ l2W, const float* __restrict__ l2b,
                      float* __restrict__ outp) {
    int g = blockIdx.x * blockDim.x + threadIdx.x;
    if (g >= NG) return;
    float c = fmaxf(cnt[g], 1.0f);
    float inv = 1.0f / c;
    float p[HID];
#pragma unroll
    for (int k = 0; k < HID; k++) p[k] = pool_sums[g * HID + k] * inv;
    float acc = 0.f;
    for (int j = 0; j < HID / 2; j++) {
        float z = l1b[j];
#pragma unroll 8
        for (int k = 0; k < HID; k++) z += p[k] * l1W[k * (HID / 2) + j];
        acc += fmaxf(z, 0.f) * l2W[j];
    }
    outp[g] = acc + l2b[0];
}

extern "C" void kernel_launch(void* const* d_in, const int* in_sizes, int n_in,
                              void* d_out, int out_size, void* d_ws, size_t ws_size,
                              hipStream_t stream) {
    const float* x   = (const float*)d_in[0];
    const int*   ei  = (const int*)d_in[1];
    const float* ew  = (const float*)d_in[2];
    const int*   bat = (const int*)d_in[3];
    const float* W1  = (const float*)d_in[4];
    const float* b1  = (const float*)d_in[5];
    const float* W2  = (const float*)d_in[6];
    const float* b2  = (const float*)d_in[7];
    const float* g1  = (const float*)d_in[8];
    const float* be1 = (const float*)d_in[9];
    const float* m1  = (const float*)d_in[10];
    const float* v1  = (const float*)d_in[11];
    const float* g2  = (const float*)d_in[12];
    const float* be2 = (const float*)d_in[13];
    const float* m2  = (const float*)d_in[14];
    const float* v2  = (const float*)d_in[15];
    const float* l1W = (const float*)d_in[16];
    const float* l1b = (const float*)d_in[17];
    const float* l2W = (const float*)d_in[18];
    const float* l2b = (const float*)d_in[19];
    float* out = (float*)d_out;

    const int* src = ei;
    const int* dst = ei + NE;

    float* f = (float*)d_ws;
    float* dinv = f;                       // NN
    float* bufA = f + 50000;               // NN*HID  (projected h)
    float* bufB = f + 3250000;             // NN*HID  (aggregated out)
    float* bufC = f + 6450000;             // NN*HID  (activated)
    float* pool = f + 9650000;             // NG*HID
    float* cnt  = f + 9658192;             // NG

    const int BLK = 256;
    const int gN    = (NN + BLK - 1) / BLK;
    const int gE    = (NE + BLK - 1) / BLK;
    const int gNH   = (NN * HID + BLK - 1) / BLK;
    const int gN16  = (NN * 16 + BLK - 1) / BLK;
    const int gE16  = (NE * 16 + BLK - 1) / BLK;

    // normalization (shared across both conv layers)
    k_deg_init<<<gN, BLK, 0, stream>>>(dinv);
    k_deg_scatter<<<gE, BLK, 0, stream>>>(dst, ew, dinv);
    k_dinv<<<gN, BLK, 0, stream>>>(dinv);

    // layer 1
    k_gemm1<<<gNH, BLK, 0, stream>>>(x, W1, bufA);
    k_init_out<<<gN16, BLK, 0, stream>>>(bufA, dinv, b1, bufB);
    k_scatter<<<gE16, BLK, 0, stream>>>(src, dst, ew, dinv, bufA, bufB);
    k_bnrelu<<<gN16, BLK, 0, stream>>>(bufB, bufC, g1, be1, m1, v1);

    // layer 2
    k_gemm2<<<gNH, BLK, 0, stream>>>(bufC, W2, bufA);
    k_init_out<<<gN16, BLK, 0, stream>>>(bufA, dinv, b2, bufB);
    k_scatter<<<gE16, BLK, 0, stream>>>(src, dst, ew, dinv, bufA, bufB);

    // pool (fused bn2+relu) + MLP
    hipMemsetAsync(pool, 0, (NG * HID + NG) * sizeof(float), stream);
    k_pool<<<gN16, BLK, 0, stream>>>(bufB, bat, g2, be2, m2, v2, pool, cnt);
    k_mlp<<<1, 128, 0, stream>>>(pool, cnt, l1W, l1b, l2W, l2b, out);
}

// Round 2
// 562.942 us; speedup vs baseline: 3.0448x; 3.0448x over previous
//
#include <hip/hip_runtime.h>

#define NN 50000
#define NE 800000
#define NG 128
#define IND 5
#define HID 64
#define EPSV 1e-5f
#define SCAN_T 1024

// ---- fused degree accumulate + dst histogram ----
__global__ void k_deg_hist(const int* __restrict__ dst, const float* __restrict__ w,
                           float* deg, int* hist /* row_ptr, counts at d+1 */) {
    int e = blockIdx.x * blockDim.x + threadIdx.x;
    if (e < NE) {
        int d = dst[e];
        atomicAdd(&deg[d], w[e]);
        atomicAdd(&hist[d + 1], 1);
    }
}

// deg was zero-init; self-loop adds 1 -> dinv = rsqrt(deg+1)
__global__ void k_dinv(float* deg) {
    int i = blockIdx.x * blockDim.x + threadIdx.x;
    if (i < NN) deg[i] = rsqrtf(deg[i] + 1.0f);
}

// ---- single-block inclusive scan of row_ptr[0..NN] (row_ptr[0]=0 pre-zeroed) ----
__global__ void k_scan(int* __restrict__ row_ptr) {
    __shared__ int tot[SCAN_T];
    int t = threadIdx.x;
    const int CH = (NN + 1 + SCAN_T - 1) / SCAN_T;
    int beg = t * CH;
    int end = beg + CH; if (end > NN + 1) end = NN + 1;
    int s = 0;
    for (int i = beg; i < end; i++) s += row_ptr[i];
    tot[t] = s;
    __syncthreads();
    for (int off = 1; off < SCAN_T; off <<= 1) {
        int v = (t >= off) ? tot[t - off] : 0;
        __syncthreads();
        tot[t] += v;
        __syncthreads();
    }
    int run = (t > 0) ? tot[t - 1] : 0;
    for (int i = beg; i < end; i++) { run += row_ptr[i]; row_ptr[i] = run; }
}

// ---- bin edges into CSR (src + fused norm), keyed by dst ----
__global__ void k_fill(const int* __restrict__ src, const int* __restrict__ dst,
                       const float* __restrict__ ew, const float* __restrict__ dinv,
                       const int* __restrict__ row_ptr, int* cursor, int2* __restrict__ csr) {
    int e = blockIdx.x * blockDim.x + threadIdx.x;
    if (e >= NE) return;
    int s = src[e], d = dst[e];
    int pos = row_ptr[d] + atomicAdd(&cursor[d], 1);
    float norm = dinv[s] * ew[e] * dinv[d];
    csr[pos] = make_int2(s, __float_as_int(norm));
}

// ---------------- x @ W1  (N x 5 @ 5 x 64) ----------------
__global__ void k_gemm1(const float* __restrict__ x, const float* __restrict__ W1,
                        float* __restrict__ h) {
    __shared__ float Ws[IND * HID];
    for (int j = threadIdx.x; j < IND * HID; j += blockDim.x) Ws[j] = W1[j];
    __syncthreads();
    int gid = blockIdx.x * blockDim.x + threadIdx.x;
    if (gid >= NN * HID) return;
    int n = gid >> 6, hc = gid & 63;
    const float* xr = &x[n * IND];
    float acc = 0.f;
#pragma unroll
    for (int k = 0; k < IND; k++) acc += xr[k] * Ws[k * HID + hc];
    h[gid] = acc;
}

// ---------------- a @ W2  (N x 64 @ 64 x 64) ----------------
__global__ void k_gemm2(const float* __restrict__ a, const float* __restrict__ W,
                        float* __restrict__ out) {
    __shared__ float Ws[HID * HID];
    for (int j = threadIdx.x; j < HID * HID; j += blockDim.x) Ws[j] = W[j];
    __syncthreads();
    int gid = blockIdx.x * blockDim.x + threadIdx.x;
    if (gid >= NN * HID) return;
    int n = gid >> 6, hc = gid & 63;
    const float* ar = &a[n * HID];
    float acc = 0.f;
#pragma unroll 8
    for (int k = 0; k < HID; k++) acc += ar[k] * Ws[k * HID + hc];
    out[gid] = acc;
}

// ---- gather aggregation + fused epilogue.  LAYER=1: bn1+relu -> outv.
//      LAYER=2: bn2+relu -> pool atomics. ----
template <int LAYER>
__global__ void k_gather(const float* __restrict__ h, const float* __restrict__ dinv,
                         const int* __restrict__ row_ptr, const int2* __restrict__ csr,
                         const float* __restrict__ bias,
                         const float* __restrict__ gamma, const float* __restrict__ beta,
                         const float* __restrict__ mean, const float* __restrict__ var,
                         const int* __restrict__ batch,
                         float* __restrict__ outv, float* pool, float* cnt) {
    int gid = blockIdx.x * blockDim.x + threadIdx.x;  // 16 lanes per node
    if (gid >= NN * 16) return;
    int n = gid >> 4, c4 = gid & 15;
    const float4* h4 = (const float4*)h;
    int beg = row_ptr[n], end = row_ptr[n + 1];
    float4 acc = make_float4(0.f, 0.f, 0.f, 0.f);
    for (int i = beg; i < end; i++) {
        int2 ef = csr[i];
        float w = __int_as_float(ef.y);
        float4 hv = h4[ef.x * 16 + c4];
        acc.x += w * hv.x; acc.y += w * hv.y; acc.z += w * hv.z; acc.w += w * hv.w;
    }
    float di = dinv[n];
    float coef = di * di;
    float4 hv = h4[n * 16 + c4];
    float4 bv = ((const float4*)bias)[c4];
    int c0 = c4 * 4;
    float v0 = bv.x + coef * hv.x + acc.x;
    float v1 = bv.y + coef * hv.y + acc.y;
    float v2 = bv.z + coef * hv.z + acc.z;
    float v3 = bv.w + coef * hv.w + acc.w;
    float r0 = fmaxf((v0 - mean[c0 + 0]) * rsqrtf(var[c0 + 0] + EPSV) * gamma[c0 + 0] + beta[c0 + 0], 0.f);
    float r1 = fmaxf((v1 - mean[c0 + 1]) * rsqrtf(var[c0 + 1] + EPSV) * gamma[c0 + 1] + beta[c0 + 1], 0.f);
    float r2 = fmaxf((v2 - mean[c0 + 2]) * rsqrtf(var[c0 + 2] + EPSV) * gamma[c0 + 2] + beta[c0 + 2], 0.f);
    float r3 = fmaxf((v3 - mean[c0 + 3]) * rsqrtf(var[c0 + 3] + EPSV) * gamma[c0 + 3] + beta[c0 + 3], 0.f);
    if (LAYER == 1) {
        ((float4*)outv)[gid] = make_float4(r0, r1, r2, r3);
    } else {
        int g = batch[n];
        float* pp = &pool[g * HID + c0];
        atomicAdd(pp + 0, r0);
        atomicAdd(pp + 1, r1);
        atomicAdd(pp + 2, r2);
        atomicAdd(pp + 3, r3);
        if (c4 == 0) atomicAdd(&cnt[g], 1.0f);
    }
}

// ---------------- final MLP ----------------
__global__ void k_mlp(const float* __restrict__ pool_sums, const float* __restrict__ cnt,
                      const float* __restrict__ l1W, const float* __restrict__ l1b,
                      const float* __restrict__ l2W, const float* __restrict__ l2b,
                      float* __restrict__ outp) {
    int g = blockIdx.x * blockDim.x + threadIdx.x;
    if (g >= NG) return;
    float c = fmaxf(cnt[g], 1.0f);
    float inv = 1.0f / c;
    float p[HID];
#pragma unroll
    for (int k = 0; k < HID; k++) p[k] = pool_sums[g * HID + k] * inv;
    float acc = 0.f;
    for (int j = 0; j < HID / 2; j++) {
        float z = l1b[j];
#pragma unroll 8
        for (int k = 0; k < HID; k++) z += p[k] * l1W[k * (HID / 2) + j];
        acc += fmaxf(z, 0.f) * l2W[j];
    }
    outp[g] = acc + l2b[0];
}

extern "C" void kernel_launch(void* const* d_in, const int* in_sizes, int n_in,
                              void* d_out, int out_size, void* d_ws, size_t ws_size,
                              hipStream_t stream) {
    const float* x   = (const float*)d_in[0];
    const int*   ei  = (const int*)d_in[1];
    const float* ew  = (const float*)d_in[2];
    const int*   bat = (const int*)d_in[3];
    const float* W1  = (const float*)d_in[4];
    const float* b1  = (const float*)d_in[5];
    const float* W2  = (const float*)d_in[6];
    const float* b2  = (const float*)d_in[7];
    const float* g1  = (const float*)d_in[8];
    const float* be1 = (const float*)d_in[9];
    const float* m1  = (const float*)d_in[10];
    const float* v1  = (const float*)d_in[11];
    const float* g2  = (const float*)d_in[12];
    const float* be2 = (const float*)d_in[13];
    const float* m2  = (const float*)d_in[14];
    const float* v2  = (const float*)d_in[15];
    const float* l1W = (const float*)d_in[16];
    const float* l1b = (const float*)d_in[17];
    const float* l2W = (const float*)d_in[18];
    const float* l2b = (const float*)d_in[19];
    float* out = (float*)d_out;

    const int* src = ei;
    const int* dst = ei + NE;

    // ---- workspace layout (4-byte units) ----
    float* f = (float*)d_ws;
    float* dinv    = f + 0;               // 50000  (zeroed; becomes rsqrt(deg+1))
    float* pool    = f + 50000;           // 8192
    float* cnt     = f + 58192;           // 128
    int*   row_ptr = (int*)(f + 58320);   // 50001
    int*   cursor  = (int*)(f + 108321);  // 50000
    // zero region = [0, 158321) floats
    int2*  csr     = (int2*)(f + 158336); // 800000 int2 (8B aligned)
    float* bufA    = f + 1758336;         // NN*HID (projected h)
    float* bufC    = f + 4958336;         // NN*HID (layer-1 activated)
    // total = 8158336 floats = 32.6 MB

    const int BLK = 256;
    const int gN   = (NN + BLK - 1) / BLK;
    const int gE   = (NE + BLK - 1) / BLK;
    const int gNH  = (NN * HID + BLK - 1) / BLK;
    const int gN16 = (NN * 16 + BLK - 1) / BLK;

    hipMemsetAsync(d_ws, 0, 158321 * sizeof(float), stream);

    // normalization + CSR build (shared across both conv layers)
    k_deg_hist<<<gE, BLK, 0, stream>>>(dst, ew, dinv, row_ptr);
    k_dinv<<<gN, BLK, 0, stream>>>(dinv);
    k_scan<<<1, SCAN_T, 0, stream>>>(row_ptr);
    k_fill<<<gE, BLK, 0, stream>>>(src, dst, ew, dinv, row_ptr, cursor, csr);

    // layer 1: project, gather(+bn1+relu fused)
    k_gemm1<<<gNH, BLK, 0, stream>>>(x, W1, bufA);
    k_gather<1><<<gN16, BLK, 0, stream>>>(bufA, dinv, row_ptr, csr, b1,
                                          g1, be1, m1, v1, bat, bufC, pool, cnt);

    // layer 2: project, gather(+bn2+relu+pool fused)
    k_gemm2<<<gNH, BLK, 0, stream>>>(bufC, W2, bufA);
    k_gather<2><<<gN16, BLK, 0, stream>>>(bufA, dinv, row_ptr, csr, b2,
                                          g2, be2, m2, v2, bat, nullptr, pool, cnt);

    // MLP head
    k_mlp<<<1, 128, 0, stream>>>(pool, cnt, l1W, l1b, l2W, l2b, out);
}